// Round 7
// baseline (208.628 us; speedup 1.0000x reference)
//
#include <hip/hip_runtime.h>
#include <hip/hip_bf16.h>
#include <math.h>

#define NB  32
#define NS  4096
#define ND  64
#define NKC 256

#define BK    128
#define ASA   132   // As row stride (shorts): 128 data + 4 pad
#define ASB   132   // Bs row stride (shorts)

#define QSTR  72
#define PBSTR 264
#define VSTR  264

#define NKE ((size_t)NB * NKC * ND)   // floats per partial buffer (2 MB)

typedef __attribute__((ext_vector_type(8))) short short8;
typedef __attribute__((ext_vector_type(4))) float f32x4;

__device__ __forceinline__ short f2bf(float f) {
    union { float f; unsigned u; } v; v.f = f;
    return (short)((v.u + 0x7FFFu + ((v.u >> 16) & 1u)) >> 16);  // RTNE
}

// ---------------------------------------------------------------------------
// prep (large-ws tier): convert Ew/Fw fp32 -> bf16.
// ---------------------------------------------------------------------------
__global__ __launch_bounds__(256) void prep(
    const float* __restrict__ Ew, const float* __restrict__ Fw,
    short* __restrict__ EwB, short* __restrict__ FwB)
{
    const int gid = blockIdx.x * 256 + threadIdx.x;       // < 262144
    const int half = (NKC * NS) / 8;                      // 131072
    const float* src = (gid < half) ? Ew : Fw;
    short* dst       = (gid < half) ? EwB : FwB;
    const int i8 = (gid < half) ? gid : gid - half;
    float4 a = *(const float4*)&src[(size_t)i8 * 8];
    float4 c = *(const float4*)&src[(size_t)i8 * 8 + 4];
    short8 w;
    w[0] = f2bf(a.x); w[1] = f2bf(a.y); w[2] = f2bf(a.z); w[3] = f2bf(a.w);
    w[4] = f2bf(c.x); w[5] = f2bf(c.y); w[6] = f2bf(c.z); w[7] = f2bf(c.w);
    *(short8*)&dst[(size_t)i8 * 8] = w;
}

// ---------------------------------------------------------------------------
// proj split-K=NSPL (template): grid NSPL*256 blocks x 256 thr, tile
// 64kc x 64d, (4096/NSPL)/128 iters. Proven R4 inner loop.
// bid = gg*32 + mt*8 + r8; grp = gg*8 + r8 = b*2*NSPL + mm*NSPL + kq.
// grp%8 = mm*NSPL+kq (NSPL=4) -> each XCD streams one (matrix, quarter);
// 4 mt-sharers of one B slab share bid%8 -> same XCD, B L2-served.
// Partial buffer q at base + q*2*NKE (KeT) / + NKE (Vf).
// ---------------------------------------------------------------------------
template <typename AT, int NSPL>
__global__ __launch_bounds__(256, 2 * NSPL / 2) void proj_sk(
    const AT* __restrict__ EwX, const AT* __restrict__ FwX,
    const float* __restrict__ K, const float* __restrict__ V,
    float* __restrict__ base)
{
    constexpr int KSEG = NS / NSPL;
    const int bid = blockIdx.x;
    const int r8 = bid & 7, mt = (bid >> 3) & 3, gg = bid >> 5;
    const int grp = gg * 8 + r8;
    const int kq = grp % NSPL, mm = (grp / NSPL) & 1, b = grp / (2 * NSPL);

    const AT* __restrict__ Ab    = mm ? FwX : EwX;  // [256][4096]
    const float* __restrict__ Bg = mm ? V   : K;    // [B][4096][64] fp32
    float* __restrict__ Cout = base + (size_t)kq * 2 * NKE + (mm ? NKE : 0);

    const int t = threadIdx.x, wave = t >> 6, lane = t & 63;
    const int lm = lane & 15, g4 = lane >> 4;
    __shared__ short As[64 * ASA];   // 16896 B
    __shared__ short Bs[64 * ASB];   // 16896 B
    const size_t bBase = (size_t)b * NS * ND;
    const size_t aBase = (size_t)mt * 64 * NS;
    const int rA = t >> 4, jA = t & 15;
    const int dB = t & 31, sB = t >> 5;

    f32x4 acc[4];
#pragma unroll
    for (int nt = 0; nt < 4; ++nt) acc[nt] = (f32x4){0.f, 0.f, 0.f, 0.f};

    short8 pa[4];
    float4 paf[8];
    float2 pb[16];

    const int sBeg = kq * KSEG, sEnd = sBeg + KSEG;

#pragma unroll
    for (int i = 0; i < 4; ++i) {
        if constexpr (sizeof(AT) == 2) {
            pa[i] = *(const short8*)&Ab[aBase + (size_t)(i * 16 + rA) * NS + sBeg + jA * 8];
        } else {
            paf[2 * i]     = *(const float4*)&Ab[aBase + (size_t)(i * 16 + rA) * NS + sBeg + jA * 8];
            paf[2 * i + 1] = *(const float4*)&Ab[aBase + (size_t)(i * 16 + rA) * NS + sBeg + jA * 8 + 4];
        }
    }
#pragma unroll
    for (int h = 0; h < 2; ++h)
#pragma unroll
        for (int i = 0; i < 8; ++i)
            pb[h * 8 + i] = *(const float2*)&Bg[bBase + (size_t)(sBeg + h * 64 + sB * 8 + i) * ND + dB * 2];

    for (int s0 = sBeg; s0 < sEnd; s0 += BK) {
#pragma unroll
        for (int i = 0; i < 4; ++i) {
            if constexpr (sizeof(AT) == 2) {
                *(short8*)&As[(i * 16 + rA) * ASA + jA * 8] = pa[i];
            } else {
                short8 w;
                w[0] = f2bf(paf[2 * i].x);     w[1] = f2bf(paf[2 * i].y);
                w[2] = f2bf(paf[2 * i].z);     w[3] = f2bf(paf[2 * i].w);
                w[4] = f2bf(paf[2 * i + 1].x); w[5] = f2bf(paf[2 * i + 1].y);
                w[6] = f2bf(paf[2 * i + 1].z); w[7] = f2bf(paf[2 * i + 1].w);
                *(short8*)&As[(i * 16 + rA) * ASA + jA * 8] = w;
            }
        }
#pragma unroll
        for (int h = 0; h < 2; ++h) {
            short8 w0, w1;
#pragma unroll
            for (int i = 0; i < 8; ++i) {
                w0[i] = f2bf(pb[h * 8 + i].x);
                w1[i] = f2bf(pb[h * 8 + i].y);
            }
            *(short8*)&Bs[(dB * 2 + 0) * ASB + h * 64 + sB * 8] = w0;
            *(short8*)&Bs[(dB * 2 + 1) * ASB + h * 64 + sB * 8] = w1;
        }
        __syncthreads();

        if (s0 + BK < sEnd) {
            const int sn = s0 + BK;
#pragma unroll
            for (int i = 0; i < 4; ++i) {
                if constexpr (sizeof(AT) == 2) {
                    pa[i] = *(const short8*)&Ab[aBase + (size_t)(i * 16 + rA) * NS + sn + jA * 8];
                } else {
                    paf[2 * i]     = *(const float4*)&Ab[aBase + (size_t)(i * 16 + rA) * NS + sn + jA * 8];
                    paf[2 * i + 1] = *(const float4*)&Ab[aBase + (size_t)(i * 16 + rA) * NS + sn + jA * 8 + 4];
                }
            }
#pragma unroll
            for (int h = 0; h < 2; ++h)
#pragma unroll
                for (int i = 0; i < 8; ++i)
                    pb[h * 8 + i] = *(const float2*)&Bg[bBase + (size_t)(sn + h * 64 + sB * 8 + i) * ND + dB * 2];
        }

#pragma unroll
        for (int ks = 0; ks < BK; ks += 32) {
            short8 aF = *(const short8*)&As[(wave * 16 + lm) * ASA + ks + g4 * 8];
#pragma unroll
            for (int nt = 0; nt < 4; ++nt) {
                short8 bF = *(const short8*)&Bs[(nt * 16 + lm) * ASB + ks + g4 * 8];
                acc[nt] = __builtin_amdgcn_mfma_f32_16x16x32_bf16(aF, bF, acc[nt], 0, 0, 0);
            }
        }
        __syncthreads();
    }

#pragma unroll
    for (int nt = 0; nt < 4; ++nt)
#pragma unroll
        for (int rr = 0; rr < 4; ++rr) {
            int kc = mt * 64 + wave * 16 + g4 * 4 + rr;
            Cout[((size_t)b * NKC + kc) * ND + nt * 16 + lm] = acc[nt][rr];
        }
}

// ---------------------------------------------------------------------------
// colsum: mv[b][d] = (sum_q sum_k Vf_q[b,k,d] + sum_k Fb[k]) / 256.
// 32 blocks x 256 threads; runs once, kills the 1920x re-read in broadcast.
// ---------------------------------------------------------------------------
template <int NQ>
__global__ __launch_bounds__(256) void colsum(
    const float* __restrict__ base, const float* __restrict__ Fb,
    float* __restrict__ mv)
{
    const int b = blockIdx.x, t = threadIdx.x;
    const int d = t & 63, ks = t >> 6;          // ks 0..3
    __shared__ float ps[4][64];
    __shared__ float fbs[64];
    float s = 0.f;
#pragma unroll
    for (int q = 0; q < NQ; ++q) {
        const float* Vq = base + (size_t)q * 2 * NKE + NKE + (size_t)b * NKC * ND;
#pragma unroll 8
        for (int k = ks * 64; k < ks * 64 + 64; ++k)
            s += Vq[(size_t)k * ND + d];
    }
    ps[ks][d] = s;
    if (t < 64) fbs[t] = Fb[t] + Fb[t + 64] + Fb[t + 128] + Fb[t + 192];
    __syncthreads();
    if (t < 64) {
        float tot = ps[0][t] + ps[1][t] + ps[2][t] + ps[3][t];
        float fbsum = 0.f;
#pragma unroll
        for (int i = 0; i < 64; ++i) fbsum += fbs[i];
        mv[(size_t)b * 64 + t] = (tot + fbsum) * (1.f / 256.f);
    }
}

// ---------------------------------------------------------------------------
// attn_fused: 256 threads (proven R5 structure), folds NF partial buffers in
// registers. USEMV: broadcast path just reads mv (16B/thread) and stores.
// grid (68, 32): x<8 heavy rows x*32..+31, x>=8 broadcast 64 rows/block.
// ---------------------------------------------------------------------------
template <int NF, bool USEMV>
__global__ __launch_bounds__(256) void attn_fused(
    const float* __restrict__ Q,  const float* __restrict__ base,
    const float* __restrict__ mv, const float* __restrict__ Eb,
    const float* __restrict__ Fb, float* __restrict__ out)
{
    const int x = blockIdx.x, b = blockIdx.y, t = threadIdx.x;

    if (x >= 8) {
        const int r0 = 256 + (x - 8) * 64;
        if constexpr (USEMV) {
            // mean precomputed by colsum: pure stores
            float4 val = *(const float4*)&mv[(size_t)b * 64 + (t & 15) * 4];
            const int rbase = t >> 4;
#pragma unroll
            for (int i = 0; i < 4; ++i)
                *(float4*)&out[((size_t)b * NS + r0 + i * 16 + rbase) * ND + (t & 15) * 4] = val;
        } else {
            __shared__ float pq[16][64];
            __shared__ float mvs[64];
            const int kg = t >> 4, dq = t & 15;
            float4 s4 = (float4){0.f, 0.f, 0.f, 0.f};
            for (int p = 0; p < 16; ++p) {
                int k = p * 16 + kg;
                float vx = 0.f, vy = 0.f, vz = 0.f, vw = 0.f;
#pragma unroll
                for (int q = 0; q < NF; ++q) {
                    const float* Vq = base + (size_t)q * 2 * NKE + NKE;
                    float4 v = *(const float4*)&Vq[((size_t)b * NKC + k) * ND + dq * 4];
                    vx += v.x; vy += v.y; vz += v.z; vw += v.w;
                }
                float fb = Fb[k];
                s4.x += vx + fb; s4.y += vy + fb; s4.z += vz + fb; s4.w += vw + fb;
            }
            *(float4*)&pq[kg][dq * 4] = s4;
            __syncthreads();
            if (t < 64) {
                float m = 0.f;
#pragma unroll
                for (int i = 0; i < 16; ++i) m += pq[i][t];
                mvs[t] = m * (1.f / 256.f);
            }
            __syncthreads();
#pragma unroll
            for (int i = 0; i < 4; ++i) {
                int idx = i * 256 + t, row = idx >> 4, q = idx & 15;
                *(float4*)&out[((size_t)b * NS + r0 + row) * ND + q * 4] =
                    *(const float4*)&mvs[q * 4];
            }
        }
        return;
    }

    const int s0 = x * 32;
    const int wave = t >> 6, lane = t & 63, lm = lane & 15, g = lane >> 4;
    __shared__ short Qs[32 * QSTR];     //  4.6 KB
    __shared__ short PsB[32 * PBSTR];   // 16.9 KB
    __shared__ short VfT[64 * VSTR];    // 33.8 KB
    __shared__ float rsums[32][4];      // [row][wave]

    // stage Q rows -> bf16
    {
        int row = t >> 3, dq = t & 7;
        size_t off = ((size_t)b * NS + s0 + row) * ND + dq * 8;
        float4 q0 = *(const float4*)&Q[off], q1 = *(const float4*)&Q[off + 4];
        short8 w;
        w[0] = f2bf(q0.x); w[1] = f2bf(q0.y); w[2] = f2bf(q0.z); w[3] = f2bf(q0.w);
        w[4] = f2bf(q1.x); w[5] = f2bf(q1.y); w[6] = f2bf(q1.z); w[7] = f2bf(q1.w);
        *(short8*)&Qs[row * QSTR + dq * 8] = w;
    }
    // stage VfT[d][k] = bf16(sum_q Vf_q[k][d] + Fb[k]); 4 passes of 64 k-rows
    {
        const int dB = t & 31, sB = t >> 5;
#pragma unroll
        for (int pass = 0; pass < 4; ++pass) {
            int kb = pass * 64 + sB * 8;
            float2 v[8]; float fb[8];
#pragma unroll
            for (int i = 0; i < 8; ++i) {
                float2 s = (float2){0.f, 0.f};
#pragma unroll
                for (int q = 0; q < NF; ++q) {
                    const float* Vq = base + (size_t)q * 2 * NKE + NKE;
                    float2 xv = *(const float2*)&Vq[((size_t)b * NKC + kb + i) * ND + dB * 2];
                    s.x += xv.x; s.y += xv.y;
                }
                v[i]  = s;
                fb[i] = Fb[kb + i];
            }
            short8 w0, w1;
#pragma unroll
            for (int i = 0; i < 8; ++i) {
                w0[i] = f2bf(v[i].x + fb[i]);
                w1[i] = f2bf(v[i].y + fb[i]);
            }
            *(short8*)&VfT[(dB * 2 + 0) * VSTR + kb] = w0;
            *(short8*)&VfT[(dB * 2 + 1) * VSTR + kb] = w1;
        }
    }
    __syncthreads();

    // phase 1: P = Q*(Ke+Eb)^T/8; wave w -> col range [w*64, w*64+64)
    f32x4 accP[2][4];
#pragma unroll
    for (int rt = 0; rt < 2; ++rt)
#pragma unroll
        for (int kk = 0; kk < 4; ++kk) accP[rt][kk] = (f32x4){0.f, 0.f, 0.f, 0.f};
#pragma unroll
    for (int kk = 0; kk < 4; ++kk) {
        int kt = wave * 4 + kk;
        float ebv = Eb[kt * 16 + lm];
#pragma unroll
        for (int ks2 = 0; ks2 < 2; ++ks2) {
            const size_t koff = ((size_t)b * NKC + kt * 16 + lm) * ND + ks2 * 32 + g * 8;
            float4 c0 = (float4){0.f, 0.f, 0.f, 0.f};
            float4 c1 = (float4){0.f, 0.f, 0.f, 0.f};
#pragma unroll
            for (int q = 0; q < NF; ++q) {
                const float* Kq = base + (size_t)q * 2 * NKE;
                float4 a0 = *(const float4*)&Kq[koff];
                float4 a1 = *(const float4*)&Kq[koff + 4];
                c0.x += a0.x; c0.y += a0.y; c0.z += a0.z; c0.w += a0.w;
                c1.x += a1.x; c1.y += a1.y; c1.z += a1.z; c1.w += a1.w;
            }
            short8 bf;
            bf[0] = f2bf(c0.x + ebv); bf[1] = f2bf(c0.y + ebv);
            bf[2] = f2bf(c0.z + ebv); bf[3] = f2bf(c0.w + ebv);
            bf[4] = f2bf(c1.x + ebv); bf[5] = f2bf(c1.y + ebv);
            bf[6] = f2bf(c1.z + ebv); bf[7] = f2bf(c1.w + ebv);
#pragma unroll
            for (int rt = 0; rt < 2; ++rt) {
                short8 aq = *(const short8*)&Qs[(rt * 16 + lm) * QSTR + ks2 * 32 + g * 8];
                accP[rt][kk] = __builtin_amdgcn_mfma_f32_16x16x32_bf16(aq, bf, accP[rt][kk], 0, 0, 0);
            }
        }
    }
    // exp (max-free: scores ~ N(0,1), no overflow) + per-row partial sums
#pragma unroll
    for (int rt = 0; rt < 2; ++rt)
#pragma unroll
        for (int r = 0; r < 4; ++r) {
            float s = 0.f;
            int rowg = s0 + rt * 16 + g * 4 + r;
#pragma unroll
            for (int kk = 0; kk < 4; ++kk) {
                int col = wave * 64 + kk * 16 + lm;
                float e = (col >= rowg) ? __expf(accP[rt][kk][r] * 0.125f) : 0.f;
                accP[rt][kk][r] = e;
                s += e;
            }
#pragma unroll
            for (int off = 1; off <= 8; off <<= 1) s += __shfl_xor(s, off, 64);
            if (lm == 0) rsums[rt * 16 + g * 4 + r][wave] = s;
        }
    __syncthreads();
    // normalize -> PsB bf16
#pragma unroll
    for (int rt = 0; rt < 2; ++rt)
#pragma unroll
        for (int r = 0; r < 4; ++r) {
            float4 rs = *(const float4*)&rsums[rt * 16 + g * 4 + r][0];
            float inv = 1.f / (rs.x + rs.y + rs.z + rs.w);
#pragma unroll
            for (int kk = 0; kk < 4; ++kk)
                PsB[(rt * 16 + g * 4 + r) * PBSTR + wave * 64 + kk * 16 + lm] =
                    f2bf(accP[rt][kk][r] * inv);
        }
    __syncthreads();

    // phase 2: out = P * VfT; k < 32x provably zero -> start at ks = x
    f32x4 oa[2];
    oa[0] = (f32x4){0.f, 0.f, 0.f, 0.f};
    oa[1] = (f32x4){0.f, 0.f, 0.f, 0.f};
    for (int ks = x; ks < 8; ++ks) {
        short8 bv = *(const short8*)&VfT[(wave * 16 + lm) * VSTR + ks * 32 + g * 8];
#pragma unroll
        for (int rt = 0; rt < 2; ++rt) {
            short8 av = *(const short8*)&PsB[(rt * 16 + lm) * PBSTR + ks * 32 + g * 8];
            oa[rt] = __builtin_amdgcn_mfma_f32_16x16x32_bf16(av, bv, oa[rt], 0, 0, 0);
        }
    }
#pragma unroll
    for (int rt = 0; rt < 2; ++rt)
#pragma unroll
        for (int r = 0; r < 4; ++r)
            out[((size_t)b * NS + s0 + rt * 16 + g * 4 + r) * ND + wave * 16 + lm] = oa[rt][r];
}

extern "C" void kernel_launch(void* const* d_in, const int* in_sizes, int n_in,
                              void* d_out, int out_size, void* d_ws, size_t ws_size,
                              hipStream_t stream) {
    (void)in_sizes; (void)n_in; (void)out_size;
    const float* Q  = (const float*)d_in[0];
    const float* K  = (const float*)d_in[1];
    const float* V  = (const float*)d_in[2];
    const float* Ew = (const float*)d_in[3];
    const float* Eb = (const float*)d_in[4];
    const float* Fw = (const float*)d_in[5];
    const float* Fb = (const float*)d_in[6];
    float* out = (float*)d_out;

    float* base = (float*)d_ws;
    const size_t MB = 1024u * 1024u;

    if (ws_size >= 21 * MB) {
        // 4 pairs (16 MB) + mv (8 KB) + bf16 weights (4 MB)
        float* mv  = base + 8 * NKE;
        short* EwB = (short*)(mv + NB * 64);
        short* FwB = EwB + (size_t)NKC * NS;
        prep<<<dim3(1024), 256, 0, stream>>>(Ew, Fw, EwB, FwB);
        proj_sk<short, 4><<<dim3(1024), 256, 0, stream>>>(EwB, FwB, K, V, base);
        colsum<4><<<dim3(NB), 256, 0, stream>>>(base, Fb, mv);
        attn_fused<4, true><<<dim3(68, NB), 256, 0, stream>>>(Q, base, mv, Eb, Fb, out);
    } else if (ws_size >= 17 * MB) {
        // 4 pairs (16 MB) + mv (8 KB), fp32 A staged in-kernel
        float* mv = base + 8 * NKE;
        proj_sk<float, 4><<<dim3(1024), 256, 0, stream>>>(Ew, Fw, K, V, base);
        colsum<4><<<dim3(NB), 256, 0, stream>>>(base, Fb, mv);
        attn_fused<4, true><<<dim3(68, NB), 256, 0, stream>>>(Q, base, mv, Eb, Fb, out);
    } else {
        // 8 MB budget: R4-proven split-2, broadcast recomputes mean
        proj_sk<float, 2><<<dim3(512), 256, 0, stream>>>(Ew, Fw, K, V, base);
        attn_fused<2, false><<<dim3(68, NB), 256, 0, stream>>>(Q, base, nullptr, Eb, Fb, out);
    }
}

// Round 8
// 183.674 us; speedup vs baseline: 1.1359x; 1.1359x over previous
//
#include <hip/hip_runtime.h>
#include <hip/hip_bf16.h>
#include <math.h>

#define NB  32
#define NS  4096
#define ND  64
#define NKC 256

#define BK    128
#define KHALF 2048
#define ASA   132   // As row stride (shorts): 128 data + 4 pad
#define ASB   132   // Bs row stride (shorts)

#define QSTR  72
#define PBSTR 264
#define VSTR  264

#define NKE ((size_t)NB * NKC * ND)   // floats per partial buffer (2 MB)

typedef __attribute__((ext_vector_type(8))) short short8;
typedef __attribute__((ext_vector_type(4))) float f32x4;

__device__ __forceinline__ short f2bf(float f) {
    union { float f; unsigned u; } v; v.f = f;
    return (short)((v.u + 0x7FFFu + ((v.u >> 16) & 1u)) >> 16);  // RTNE
}

// ---------------------------------------------------------------------------
// proj (R4/R6-proven verbatim): split-K=2, no atomics, 512 blocks x 256 thr =
// 2 blocks/CU. fp32 A converted in staging. Partials -> per-half buffers.
// ---------------------------------------------------------------------------
template <typename AT>
__global__ __launch_bounds__(256, 2) void proj_sk(
    const AT* __restrict__ EwX, const AT* __restrict__ FwX,
    const float* __restrict__ K, const float* __restrict__ V,
    float* __restrict__ base)
{
    const int bid = blockIdx.x;
    const int r8 = bid & 7, mt = (bid >> 3) & 3, gq = bid >> 5;  // gq 0..15
    const int grp = gq * 8 + r8;                                 // 0..127
    const int kh = grp & 1, mm = (grp >> 1) & 1, b = grp >> 2;

    const AT* __restrict__ Ab    = mm ? FwX : EwX;  // [256][4096]
    const float* __restrict__ Bg = mm ? V   : K;    // [B][4096][64] fp32
    float* __restrict__ Cout = base + (size_t)kh * 2 * NKE + (mm ? NKE : 0);

    const int t = threadIdx.x, wave = t >> 6, lane = t & 63;
    const int lm = lane & 15, g4 = lane >> 4;
    __shared__ short As[64 * ASA];   // 16896 B
    __shared__ short Bs[64 * ASB];   // 16896 B
    const size_t bBase = (size_t)b * NS * ND;
    const size_t aBase = (size_t)mt * 64 * NS;
    const int rA = t >> 4, jA = t & 15;
    const int dB = t & 31, sB = t >> 5;

    f32x4 acc[4];
#pragma unroll
    for (int nt = 0; nt < 4; ++nt) acc[nt] = (f32x4){0.f, 0.f, 0.f, 0.f};

    short8 pa[4];
    float4 paf[8];
    float2 pb[16];

    const int sBeg = kh * KHALF, sEnd = sBeg + KHALF;

#pragma unroll
    for (int i = 0; i < 4; ++i) {
        if constexpr (sizeof(AT) == 2) {
            pa[i] = *(const short8*)&Ab[aBase + (size_t)(i * 16 + rA) * NS + sBeg + jA * 8];
        } else {
            paf[2 * i]     = *(const float4*)&Ab[aBase + (size_t)(i * 16 + rA) * NS + sBeg + jA * 8];
            paf[2 * i + 1] = *(const float4*)&Ab[aBase + (size_t)(i * 16 + rA) * NS + sBeg + jA * 8 + 4];
        }
    }
#pragma unroll
    for (int h = 0; h < 2; ++h)
#pragma unroll
        for (int i = 0; i < 8; ++i)
            pb[h * 8 + i] = *(const float2*)&Bg[bBase + (size_t)(sBeg + h * 64 + sB * 8 + i) * ND + dB * 2];

    for (int s0 = sBeg; s0 < sEnd; s0 += BK) {
#pragma unroll
        for (int i = 0; i < 4; ++i) {
            if constexpr (sizeof(AT) == 2) {
                *(short8*)&As[(i * 16 + rA) * ASA + jA * 8] = pa[i];
            } else {
                short8 w;
                w[0] = f2bf(paf[2 * i].x);     w[1] = f2bf(paf[2 * i].y);
                w[2] = f2bf(paf[2 * i].z);     w[3] = f2bf(paf[2 * i].w);
                w[4] = f2bf(paf[2 * i + 1].x); w[5] = f2bf(paf[2 * i + 1].y);
                w[6] = f2bf(paf[2 * i + 1].z); w[7] = f2bf(paf[2 * i + 1].w);
                *(short8*)&As[(i * 16 + rA) * ASA + jA * 8] = w;
            }
        }
#pragma unroll
        for (int h = 0; h < 2; ++h) {
            short8 w0, w1;
#pragma unroll
            for (int i = 0; i < 8; ++i) {
                w0[i] = f2bf(pb[h * 8 + i].x);
                w1[i] = f2bf(pb[h * 8 + i].y);
            }
            *(short8*)&Bs[(dB * 2 + 0) * ASB + h * 64 + sB * 8] = w0;
            *(short8*)&Bs[(dB * 2 + 1) * ASB + h * 64 + sB * 8] = w1;
        }
        __syncthreads();

        if (s0 + BK < sEnd) {
            const int sn = s0 + BK;
#pragma unroll
            for (int i = 0; i < 4; ++i) {
                if constexpr (sizeof(AT) == 2) {
                    pa[i] = *(const short8*)&Ab[aBase + (size_t)(i * 16 + rA) * NS + sn + jA * 8];
                } else {
                    paf[2 * i]     = *(const float4*)&Ab[aBase + (size_t)(i * 16 + rA) * NS + sn + jA * 8];
                    paf[2 * i + 1] = *(const float4*)&Ab[aBase + (size_t)(i * 16 + rA) * NS + sn + jA * 8 + 4];
                }
            }
#pragma unroll
            for (int h = 0; h < 2; ++h)
#pragma unroll
                for (int i = 0; i < 8; ++i)
                    pb[h * 8 + i] = *(const float2*)&Bg[bBase + (size_t)(sn + h * 64 + sB * 8 + i) * ND + dB * 2];
        }

#pragma unroll
        for (int ks = 0; ks < BK; ks += 32) {
            short8 aF = *(const short8*)&As[(wave * 16 + lm) * ASA + ks + g4 * 8];
#pragma unroll
            for (int nt = 0; nt < 4; ++nt) {
                short8 bF = *(const short8*)&Bs[(nt * 16 + lm) * ASB + ks + g4 * 8];
                acc[nt] = __builtin_amdgcn_mfma_f32_16x16x32_bf16(aF, bF, acc[nt], 0, 0, 0);
            }
        }
        __syncthreads();
    }

#pragma unroll
    for (int nt = 0; nt < 4; ++nt)
#pragma unroll
        for (int rr = 0; rr < 4; ++rr) {
            int kc = mt * 64 + wave * 16 + g4 * 4 + rr;
            Cout[((size_t)b * NKC + kc) * ND + nt * 16 + lm] = acc[nt][rr];
        }
}

// ---------------------------------------------------------------------------
// fuse: fold split-K partials ONCE into MFMA-ready operands.
//   KeB[b][kc][d] = bf16(KeTa+KeTb+Eb[kc])           (1 MB)
//   VtB[b][d][kc] = bf16(Vfa+Vfb+Fb[kc]) transposed  (1 MB)
//   ps[b][x][d]   = sum over this block's 16 kc of fp32 (Vf+Fb)
// grid (16, 32) x 256 thr: block = 16 kc rows of one b.
// ---------------------------------------------------------------------------
__global__ __launch_bounds__(256) void fuse(
    const float* __restrict__ base, const float* __restrict__ Eb,
    const float* __restrict__ Fb, short* __restrict__ KeB,
    short* __restrict__ VtB, float* __restrict__ ps)
{
    const int x = blockIdx.x, b = blockIdx.y, t = threadIdx.x;
    const int kb = x * 16;
    const float* Ka  = base;
    const float* Va  = base + NKE;
    const float* Kb_ = base + 2 * NKE;
    const float* Vb  = base + 3 * NKE;
    __shared__ float vt[16][65];
    const int kci = t >> 6, d = t & 63;   // kci 0..3, 4 rows each

#pragma unroll
    for (int i = 0; i < 4; ++i) {
        int kc = kb + kci * 4 + i;
        size_t off = ((size_t)b * NKC + kc) * ND + d;
        KeB[off] = f2bf(Ka[off] + Kb_[off] + Eb[kc]);
        vt[kci * 4 + i][d] = Va[off] + Vb[off] + Fb[kc];
    }
    __syncthreads();
    if (t < 64) {
        float s = 0.f;
        short8 w0, w1;
#pragma unroll
        for (int i = 0; i < 8; ++i) { float v = vt[i][t];     s += v; w0[i] = f2bf(v); }
#pragma unroll
        for (int i = 0; i < 8; ++i) { float v = vt[8 + i][t]; s += v; w1[i] = f2bf(v); }
        ps[((size_t)b * 16 + x) * 64 + t] = s;
        short* dst = &VtB[((size_t)b * ND + t) * NKC + kb];
        *(short8*)&dst[0] = w0;
        *(short8*)&dst[8] = w1;
    }
}

// ---------------------------------------------------------------------------
// attn_new: heavy path reads MFMA-ready bf16 KeB/VtB (no fold, no bias add,
// no fp32->bf16 on the critical path); broadcast reads ps (4 KB) not panels.
// grid (68, 32): x<8 heavy rows x*32..+31, x>=8 broadcast 64 rows/block.
// ---------------------------------------------------------------------------
__global__ __launch_bounds__(256) void attn_new(
    const float* __restrict__ Q,  const short* __restrict__ KeB,
    const short* __restrict__ VtB, const float* __restrict__ ps,
    float* __restrict__ out)
{
    const int x = blockIdx.x, b = blockIdx.y, t = threadIdx.x;

    if (x >= 8) {
        __shared__ float mvs[64];
        if (t < 64) {
            float s = 0.f;
#pragma unroll
            for (int i = 0; i < 16; ++i) s += ps[((size_t)b * 16 + i) * 64 + t];
            mvs[t] = s * (1.f / 256.f);
        }
        __syncthreads();
        const int r0 = 256 + (x - 8) * 64;
#pragma unroll
        for (int i = 0; i < 4; ++i) {
            int idx = i * 256 + t, row = idx >> 4, q = idx & 15;
            *(float4*)&out[((size_t)b * NS + r0 + row) * ND + q * 4] =
                *(const float4*)&mvs[q * 4];
        }
        return;
    }

    const int s0 = x * 32;
    const int wave = t >> 6, lane = t & 63, lm = lane & 15, g = lane >> 4;
    __shared__ short Qs[32 * QSTR];     //  4.6 KB
    __shared__ short PsB[32 * PBSTR];   // 16.9 KB
    __shared__ short VfT[64 * VSTR];    // 33.8 KB
    __shared__ float rsums[32][4];      // [row][wave]

    // stage Q rows -> bf16
    {
        int row = t >> 3, dq = t & 7;
        size_t off = ((size_t)b * NS + s0 + row) * ND + dq * 8;
        float4 q0 = *(const float4*)&Q[off], q1 = *(const float4*)&Q[off + 4];
        short8 w;
        w[0] = f2bf(q0.x); w[1] = f2bf(q0.y); w[2] = f2bf(q0.z); w[3] = f2bf(q0.w);
        w[4] = f2bf(q1.x); w[5] = f2bf(q1.y); w[6] = f2bf(q1.z); w[7] = f2bf(q1.w);
        *(short8*)&Qs[row * QSTR + dq * 8] = w;
    }
    // stage VfT: straight bf16 copy of VtB[b][d][0..255] (32 KB)
    {
        const int d = t >> 2, q4 = t & 3;
        const short* src = &VtB[((size_t)b * ND + d) * NKC + q4 * 64];
#pragma unroll
        for (int i = 0; i < 8; ++i)
            *(short8*)&VfT[d * VSTR + q4 * 64 + i * 8] = *(const short8*)&src[i * 8];
    }
    __syncthreads();

    // phase 1: P = Q*(Ke+Eb)^T/8; wave w -> cols [w*64, +64); B-frag = direct
    // short8 load from KeB (bias already folded, bf16 already converted)
    f32x4 accP[2][4];
#pragma unroll
    for (int rt = 0; rt < 2; ++rt)
#pragma unroll
        for (int kk = 0; kk < 4; ++kk) accP[rt][kk] = (f32x4){0.f, 0.f, 0.f, 0.f};
#pragma unroll
    for (int kk = 0; kk < 4; ++kk) {
        int kt = wave * 4 + kk;
#pragma unroll
        for (int ks2 = 0; ks2 < 2; ++ks2) {
            short8 bf = *(const short8*)&KeB[((size_t)b * NKC + kt * 16 + lm) * ND + ks2 * 32 + g * 8];
#pragma unroll
            for (int rt = 0; rt < 2; ++rt) {
                short8 aq = *(const short8*)&Qs[(rt * 16 + lm) * QSTR + ks2 * 32 + g * 8];
                accP[rt][kk] = __builtin_amdgcn_mfma_f32_16x16x32_bf16(aq, bf, accP[rt][kk], 0, 0, 0);
            }
        }
    }
    // exp (max-free) + per-row partial sums
#pragma unroll
    for (int rt = 0; rt < 2; ++rt)
#pragma unroll
        for (int r = 0; r < 4; ++r) {
            float s = 0.f;
            int rowg = s0 + rt * 16 + g * 4 + r;
#pragma unroll
            for (int kk = 0; kk < 4; ++kk) {
                int col = wave * 64 + kk * 16 + lm;
                float e = (col >= rowg) ? __expf(accP[rt][kk][r] * 0.125f) : 0.f;
                accP[rt][kk][r] = e;
                s += e;
            }
#pragma unroll
            for (int off = 1; off <= 8; off <<= 1) s += __shfl_xor(s, off, 64);
            if (lm == 0) rsums[rt * 16 + g * 4 + r][wave] = s;
        }
    __syncthreads();
    // normalize -> PsB bf16
#pragma unroll
    for (int rt = 0; rt < 2; ++rt)
#pragma unroll
        for (int r = 0; r < 4; ++r) {
            float4 rs = *(const float4*)&rsums[rt * 16 + g * 4 + r][0];
            float inv = 1.f / (rs.x + rs.y + rs.z + rs.w);
#pragma unroll
            for (int kk = 0; kk < 4; ++kk)
                PsB[(rt * 16 + g * 4 + r) * PBSTR + wave * 64 + kk * 16 + lm] =
                    f2bf(accP[rt][kk][r] * inv);
        }
    __syncthreads();

    // phase 2: out = P * VfT; k < 32x provably zero -> start at ks = x
    f32x4 oa[2];
    oa[0] = (f32x4){0.f, 0.f, 0.f, 0.f};
    oa[1] = (f32x4){0.f, 0.f, 0.f, 0.f};
    for (int ks = x; ks < 8; ++ks) {
        short8 bv = *(const short8*)&VfT[(wave * 16 + lm) * VSTR + ks * 32 + g * 8];
#pragma unroll
        for (int rt = 0; rt < 2; ++rt) {
            short8 av = *(const short8*)&PsB[(rt * 16 + lm) * PBSTR + ks * 32 + g * 8];
            oa[rt] = __builtin_amdgcn_mfma_f32_16x16x32_bf16(av, bv, oa[rt], 0, 0, 0);
        }
    }
#pragma unroll
    for (int rt = 0; rt < 2; ++rt)
#pragma unroll
        for (int r = 0; r < 4; ++r)
            out[((size_t)b * NS + s0 + rt * 16 + g * 4 + r) * ND + wave * 16 + lm] = oa[rt][r];
}

// ---------------------------------------------------------------------------
// attn_old (fallback tier, R6-proven): folds 2 partials in registers,
// broadcast recomputes mean from Vf panels.
// ---------------------------------------------------------------------------
__global__ __launch_bounds__(256) void attn_old(
    const float* __restrict__ Q,  const float* __restrict__ base,
    const float* __restrict__ Eb, const float* __restrict__ Fb,
    float* __restrict__ out)
{
    const int x = blockIdx.x, b = blockIdx.y, t = threadIdx.x;
    const float* KeTa = base;
    const float* Vfa  = base + NKE;
    const float* KeTb = base + 2 * NKE;
    const float* Vfb  = base + 3 * NKE;

    if (x >= 8) {
        __shared__ float pq[16][64];
        __shared__ float mvs[64];
        const int kg = t >> 4, dq = t & 15;
        float4 s4 = (float4){0.f, 0.f, 0.f, 0.f};
        for (int p = 0; p < 16; ++p) {
            int k = p * 16 + kg;
            float4 v = *(const float4*)&Vfa[((size_t)b * NKC + k) * ND + dq * 4];
            float4 u = *(const float4*)&Vfb[((size_t)b * NKC + k) * ND + dq * 4];
            float fb = Fb[k];
            s4.x += (v.x + u.x) + fb; s4.y += (v.y + u.y) + fb;
            s4.z += (v.z + u.z) + fb; s4.w += (v.w + u.w) + fb;
        }
        *(float4*)&pq[kg][dq * 4] = s4;
        __syncthreads();
        if (t < 64) {
            float m = 0.f;
#pragma unroll
            for (int i = 0; i < 16; ++i) m += pq[i][t];
            mvs[t] = m * (1.f / 256.f);
        }
        __syncthreads();
        const int r0 = 256 + (x - 8) * 64;
#pragma unroll
        for (int i = 0; i < 4; ++i) {
            int idx = i * 256 + t, row = idx >> 4, q = idx & 15;
            *(float4*)&out[((size_t)b * NS + r0 + row) * ND + q * 4] =
                *(const float4*)&mvs[q * 4];
        }
        return;
    }

    const int s0 = x * 32;
    const int wave = t >> 6, lane = t & 63, lm = lane & 15, g = lane >> 4;
    __shared__ short Qs[32 * QSTR];
    __shared__ short PsB[32 * PBSTR];
    __shared__ short VfT[64 * VSTR];
    __shared__ float rsums[32][4];

    {
        int row = t >> 3, dq = t & 7;
        size_t off = ((size_t)b * NS + s0 + row) * ND + dq * 8;
        float4 q0 = *(const float4*)&Q[off], q1 = *(const float4*)&Q[off + 4];
        short8 w;
        w[0] = f2bf(q0.x); w[1] = f2bf(q0.y); w[2] = f2bf(q0.z); w[3] = f2bf(q0.w);
        w[4] = f2bf(q1.x); w[5] = f2bf(q1.y); w[6] = f2bf(q1.z); w[7] = f2bf(q1.w);
        *(short8*)&Qs[row * QSTR + dq * 8] = w;
    }
    {
        const int dB = t & 31, sB = t >> 5;
#pragma unroll
        for (int pass = 0; pass < 4; ++pass) {
            int kb = pass * 64 + sB * 8;
            float2 v[8]; float fb[8];
#pragma unroll
            for (int i = 0; i < 8; ++i) {
                float2 a = *(const float2*)&Vfa[((size_t)b * NKC + kb + i) * ND + dB * 2];
                float2 c = *(const float2*)&Vfb[((size_t)b * NKC + kb + i) * ND + dB * 2];
                v[i]  = (float2){a.x + c.x, a.y + c.y};
                fb[i] = Fb[kb + i];
            }
            short8 w0, w1;
#pragma unroll
            for (int i = 0; i < 8; ++i) {
                w0[i] = f2bf(v[i].x + fb[i]);
                w1[i] = f2bf(v[i].y + fb[i]);
            }
            *(short8*)&VfT[(dB * 2 + 0) * VSTR + kb] = w0;
            *(short8*)&VfT[(dB * 2 + 1) * VSTR + kb] = w1;
        }
    }
    __syncthreads();

    f32x4 accP[2][4];
#pragma unroll
    for (int rt = 0; rt < 2; ++rt)
#pragma unroll
        for (int kk = 0; kk < 4; ++kk) accP[rt][kk] = (f32x4){0.f, 0.f, 0.f, 0.f};
#pragma unroll
    for (int kk = 0; kk < 4; ++kk) {
        int kt = wave * 4 + kk;
        float ebv = Eb[kt * 16 + lm];
#pragma unroll
        for (int ks2 = 0; ks2 < 2; ++ks2) {
            const size_t koff = ((size_t)b * NKC + kt * 16 + lm) * ND + ks2 * 32 + g * 8;
            float4 c0 = *(const float4*)&KeTa[koff], c1 = *(const float4*)&KeTa[koff + 4];
            float4 e0 = *(const float4*)&KeTb[koff], e1 = *(const float4*)&KeTb[koff + 4];
            short8 bf;
            bf[0] = f2bf((c0.x + e0.x) + ebv); bf[1] = f2bf((c0.y + e0.y) + ebv);
            bf[2] = f2bf((c0.z + e0.z) + ebv); bf[3] = f2bf((c0.w + e0.w) + ebv);
            bf[4] = f2bf((c1.x + e1.x) + ebv); bf[5] = f2bf((c1.y + e1.y) + ebv);
            bf[6] = f2bf((c1.z + e1.z) + ebv); bf[7] = f2bf((c1.w + e1.w) + ebv);
#pragma unroll
            for (int rt = 0; rt < 2; ++rt) {
                short8 aq = *(const short8*)&Qs[(rt * 16 + lm) * QSTR + ks2 * 32 + g * 8];
                accP[rt][kk] = __builtin_amdgcn_mfma_f32_16x16x32_bf16(aq, bf, accP[rt][kk], 0, 0, 0);
            }
        }
    }
#pragma unroll
    for (int rt = 0; rt < 2; ++rt)
#pragma unroll
        for (int r = 0; r < 4; ++r) {
            float s = 0.f;
            int rowg = s0 + rt * 16 + g * 4 + r;
#pragma unroll
            for (int kk = 0; kk < 4; ++kk) {
                int col = wave * 64 + kk * 16 + lm;
                float e = (col >= rowg) ? __expf(accP[rt][kk][r] * 0.125f) : 0.f;
                accP[rt][kk][r] = e;
                s += e;
            }
#pragma unroll
            for (int off = 1; off <= 8; off <<= 1) s += __shfl_xor(s, off, 64);
            if (lm == 0) rsums[rt * 16 + g * 4 + r][wave] = s;
        }
    __syncthreads();
#pragma unroll
    for (int rt = 0; rt < 2; ++rt)
#pragma unroll
        for (int r = 0; r < 4; ++r) {
            float4 rs = *(const float4*)&rsums[rt * 16 + g * 4 + r][0];
            float inv = 1.f / (rs.x + rs.y + rs.z + rs.w);
#pragma unroll
            for (int kk = 0; kk < 4; ++kk)
                PsB[(rt * 16 + g * 4 + r) * PBSTR + wave * 64 + kk * 16 + lm] =
                    f2bf(accP[rt][kk][r] * inv);
        }
    __syncthreads();

    f32x4 oa[2];
    oa[0] = (f32x4){0.f, 0.f, 0.f, 0.f};
    oa[1] = (f32x4){0.f, 0.f, 0.f, 0.f};
    for (int ks = x; ks < 8; ++ks) {
        short8 bv = *(const short8*)&VfT[(wave * 16 + lm) * VSTR + ks * 32 + g * 8];
#pragma unroll
        for (int rt = 0; rt < 2; ++rt) {
            short8 av = *(const short8*)&PsB[(rt * 16 + lm) * PBSTR + ks * 32 + g * 8];
            oa[rt] = __builtin_amdgcn_mfma_f32_16x16x32_bf16(av, bv, oa[rt], 0, 0, 0);
        }
    }
#pragma unroll
    for (int rt = 0; rt < 2; ++rt)
#pragma unroll
        for (int r = 0; r < 4; ++r)
            out[((size_t)b * NS + s0 + rt * 16 + g * 4 + r) * ND + wave * 16 + lm] = oa[rt][r];
}

extern "C" void kernel_launch(void* const* d_in, const int* in_sizes, int n_in,
                              void* d_out, int out_size, void* d_ws, size_t ws_size,
                              hipStream_t stream) {
    (void)in_sizes; (void)n_in; (void)out_size;
    const float* Q  = (const float*)d_in[0];
    const float* K  = (const float*)d_in[1];
    const float* V  = (const float*)d_in[2];
    const float* Ew = (const float*)d_in[3];
    const float* Eb = (const float*)d_in[4];
    const float* Fw = (const float*)d_in[5];
    const float* Fb = (const float*)d_in[6];
    float* out = (float*)d_out;

    float* base = (float*)d_ws;
    const size_t MB = 1024u * 1024u;

    proj_sk<float><<<dim3(512), 256, 0, stream>>>(Ew, Fw, K, V, base);

    if (ws_size >= 11 * MB) {
        // partials 8 MB | KeB 1 MB | VtB 1 MB | ps 128 KB  (10.2 MB)
        short* KeB = (short*)(base + 4 * NKE);
        short* VtB = KeB + NKE;
        float* ps  = (float*)(VtB + NKE);
        fuse<<<dim3(16, NB), 256, 0, stream>>>(base, Eb, Fb, KeB, VtB, ps);
        attn_new<<<dim3(68, NB), 256, 0, stream>>>(Q, KeB, VtB, ps, out);
    } else {
        attn_old<<<dim3(68, NB), 256, 0, stream>>>(Q, base, Eb, Fb, out);
    }
}

// Round 9
// 170.726 us; speedup vs baseline: 1.2220x; 1.0758x over previous
//
#include <hip/hip_runtime.h>
#include <hip/hip_bf16.h>
#include <math.h>

#define NB  32
#define NS  4096
#define ND  64
#define NKC 256

#define BK    128
#define KHALF 2048
#define ASA   132   // As row stride (shorts): 128 data + 4 pad
#define ASB   132   // Bs row stride (shorts)

#define QSTR  72
#define PBSTR 264
#define VSTR  264

#define NKE ((size_t)NB * NKC * ND)   // floats per partial buffer (2 MB)

typedef __attribute__((ext_vector_type(8))) short short8;
typedef __attribute__((ext_vector_type(4))) float f32x4;

__device__ __forceinline__ short f2bf(float f) {
    union { float f; unsigned u; } v; v.f = f;
    return (short)((v.u + 0x7FFFu + ((v.u >> 16) & 1u)) >> 16);  // RTNE
}

// ---------------------------------------------------------------------------
// prep: convert Ew/Fw fp32 -> bf16 (restores the proven bf16-A proj path:
// R8 measured fp32-A staging at +10.5 us vs R4/R6's bf16-A).
// ---------------------------------------------------------------------------
__global__ __launch_bounds__(256) void prep(
    const float* __restrict__ Ew, const float* __restrict__ Fw,
    short* __restrict__ EwB, short* __restrict__ FwB)
{
    const int gid = blockIdx.x * 256 + threadIdx.x;       // < 262144
    const int half = (NKC * NS) / 8;                      // 131072
    const float* src = (gid < half) ? Ew : Fw;
    short* dst       = (gid < half) ? EwB : FwB;
    const int i8 = (gid < half) ? gid : gid - half;
    float4 a = *(const float4*)&src[(size_t)i8 * 8];
    float4 c = *(const float4*)&src[(size_t)i8 * 8 + 4];
    short8 w;
    w[0] = f2bf(a.x); w[1] = f2bf(a.y); w[2] = f2bf(a.z); w[3] = f2bf(a.w);
    w[4] = f2bf(c.x); w[5] = f2bf(c.y); w[6] = f2bf(c.z); w[7] = f2bf(c.w);
    *(short8*)&dst[(size_t)i8 * 8] = w;
}

// ---------------------------------------------------------------------------
// proj (R4-proven structure): split-K=2, no atomics, 512 blocks x 256 thr =
// 2 blocks/CU. B prefetch now float4 (8 instrs/iter vs 16 float2).
// bid = gq*32 + mt*8 + r8; grp = gq*8 + r8 = ((b*2+mm)*2+kh).
// ---------------------------------------------------------------------------
template <typename AT>
__global__ __launch_bounds__(256, 2) void proj_sk(
    const AT* __restrict__ EwX, const AT* __restrict__ FwX,
    const float* __restrict__ K, const float* __restrict__ V,
    float* __restrict__ base)
{
    const int bid = blockIdx.x;
    const int r8 = bid & 7, mt = (bid >> 3) & 3, gq = bid >> 5;  // gq 0..15
    const int grp = gq * 8 + r8;                                 // 0..127
    const int kh = grp & 1, mm = (grp >> 1) & 1, b = grp >> 2;

    const AT* __restrict__ Ab    = mm ? FwX : EwX;  // [256][4096]
    const float* __restrict__ Bg = mm ? V   : K;    // [B][4096][64] fp32
    float* __restrict__ Cout = base + (size_t)kh * 2 * NKE + (mm ? NKE : 0);

    const int t = threadIdx.x, wave = t >> 6, lane = t & 63;
    const int lm = lane & 15, g4 = lane >> 4;
    __shared__ short As[64 * ASA];   // 16896 B
    __shared__ short Bs[64 * ASB];   // 16896 B
    const size_t bBase = (size_t)b * NS * ND;
    const size_t aBase = (size_t)mt * 64 * NS;
    const int rA = t >> 4, jA = t & 15;   // A staging: 16 rows/pass, 16 col-octets
    const int dQ = t & 15, sG = t >> 4;   // B staging: d-quad, s-octet (0..15)

    f32x4 acc[4];
#pragma unroll
    for (int nt = 0; nt < 4; ++nt) acc[nt] = (f32x4){0.f, 0.f, 0.f, 0.f};

    short8 pa[4];
    float4 paf[8];
    float4 pbv[8];   // B: 8 s-rows x 4 d (one float4 per s-row)

    const int sBeg = kh * KHALF, sEnd = sBeg + KHALF;

#pragma unroll
    for (int i = 0; i < 4; ++i) {
        if constexpr (sizeof(AT) == 2) {
            pa[i] = *(const short8*)&Ab[aBase + (size_t)(i * 16 + rA) * NS + sBeg + jA * 8];
        } else {
            paf[2 * i]     = *(const float4*)&Ab[aBase + (size_t)(i * 16 + rA) * NS + sBeg + jA * 8];
            paf[2 * i + 1] = *(const float4*)&Ab[aBase + (size_t)(i * 16 + rA) * NS + sBeg + jA * 8 + 4];
        }
    }
#pragma unroll
    for (int i = 0; i < 8; ++i)
        pbv[i] = *(const float4*)&Bg[bBase + (size_t)(sBeg + sG * 8 + i) * ND + dQ * 4];

    for (int s0 = sBeg; s0 < sEnd; s0 += BK) {
        // ---- stage regs -> LDS ----
#pragma unroll
        for (int i = 0; i < 4; ++i) {
            if constexpr (sizeof(AT) == 2) {
                *(short8*)&As[(i * 16 + rA) * ASA + jA * 8] = pa[i];
            } else {
                short8 w;
                w[0] = f2bf(paf[2 * i].x);     w[1] = f2bf(paf[2 * i].y);
                w[2] = f2bf(paf[2 * i].z);     w[3] = f2bf(paf[2 * i].w);
                w[4] = f2bf(paf[2 * i + 1].x); w[5] = f2bf(paf[2 * i + 1].y);
                w[6] = f2bf(paf[2 * i + 1].z); w[7] = f2bf(paf[2 * i + 1].w);
                *(short8*)&As[(i * 16 + rA) * ASA + jA * 8] = w;
            }
        }
        {
            short8 w0, w1, w2, w3;
#pragma unroll
            for (int i = 0; i < 8; ++i) {
                w0[i] = f2bf(pbv[i].x); w1[i] = f2bf(pbv[i].y);
                w2[i] = f2bf(pbv[i].z); w3[i] = f2bf(pbv[i].w);
            }
            *(short8*)&Bs[(dQ * 4 + 0) * ASB + sG * 8] = w0;
            *(short8*)&Bs[(dQ * 4 + 1) * ASB + sG * 8] = w1;
            *(short8*)&Bs[(dQ * 4 + 2) * ASB + sG * 8] = w2;
            *(short8*)&Bs[(dQ * 4 + 3) * ASB + sG * 8] = w3;
        }
        __syncthreads();

        // ---- issue next-iter global loads (land during MFMA below) ----
        if (s0 + BK < sEnd) {
            const int sn = s0 + BK;
#pragma unroll
            for (int i = 0; i < 4; ++i) {
                if constexpr (sizeof(AT) == 2) {
                    pa[i] = *(const short8*)&Ab[aBase + (size_t)(i * 16 + rA) * NS + sn + jA * 8];
                } else {
                    paf[2 * i]     = *(const float4*)&Ab[aBase + (size_t)(i * 16 + rA) * NS + sn + jA * 8];
                    paf[2 * i + 1] = *(const float4*)&Ab[aBase + (size_t)(i * 16 + rA) * NS + sn + jA * 8 + 4];
                }
            }
#pragma unroll
            for (int i = 0; i < 8; ++i)
                pbv[i] = *(const float4*)&Bg[bBase + (size_t)(sn + sG * 8 + i) * ND + dQ * 4];
        }

        // ---- MFMA over BK=128 (4 k-steps of 32) ----
#pragma unroll
        for (int ks = 0; ks < BK; ks += 32) {
            short8 aF = *(const short8*)&As[(wave * 16 + lm) * ASA + ks + g4 * 8];
#pragma unroll
            for (int nt = 0; nt < 4; ++nt) {
                short8 bF = *(const short8*)&Bs[(nt * 16 + lm) * ASB + ks + g4 * 8];
                acc[nt] = __builtin_amdgcn_mfma_f32_16x16x32_bf16(aF, bF, acc[nt], 0, 0, 0);
            }
        }
        __syncthreads();
    }

#pragma unroll
    for (int nt = 0; nt < 4; ++nt)
#pragma unroll
        for (int rr = 0; rr < 4; ++rr) {
            int kc = mt * 64 + wave * 16 + g4 * 4 + rr;
            Cout[((size_t)b * NKC + kc) * ND + nt * 16 + lm] = acc[nt][rr];
        }
}

// ---------------------------------------------------------------------------
// fuse (R8-proven): fold split-K partials ONCE into MFMA-ready operands.
//   KeB[b][kc][d] = bf16(KeTa+KeTb+Eb[kc])           (1 MB)
//   VtB[b][d][kc] = bf16(Vfa+Vfb+Fb[kc]) transposed  (1 MB)
//   ps[b][x][d]   = fp32 colsum of this block's 16 kc of (Vf+Fb)
// grid (16, 32) x 256 thr.
// ---------------------------------------------------------------------------
__global__ __launch_bounds__(256) void fuse(
    const float* __restrict__ base, const float* __restrict__ Eb,
    const float* __restrict__ Fb, short* __restrict__ KeB,
    short* __restrict__ VtB, float* __restrict__ ps)
{
    const int x = blockIdx.x, b = blockIdx.y, t = threadIdx.x;
    const int kb = x * 16;
    const float* Ka  = base;
    const float* Va  = base + NKE;
    const float* Kb_ = base + 2 * NKE;
    const float* Vb  = base + 3 * NKE;
    __shared__ float vt[16][65];
    const int kci = t >> 6, d = t & 63;   // kci 0..3, 4 rows each

#pragma unroll
    for (int i = 0; i < 4; ++i) {
        int kc = kb + kci * 4 + i;
        size_t off = ((size_t)b * NKC + kc) * ND + d;
        KeB[off] = f2bf(Ka[off] + Kb_[off] + Eb[kc]);
        vt[kci * 4 + i][d] = Va[off] + Vb[off] + Fb[kc];
    }
    __syncthreads();
    if (t < 64) {
        float s = 0.f;
        short8 w0, w1;
#pragma unroll
        for (int i = 0; i < 8; ++i) { float v = vt[i][t];     s += v; w0[i] = f2bf(v); }
#pragma unroll
        for (int i = 0; i < 8; ++i) { float v = vt[8 + i][t]; s += v; w1[i] = f2bf(v); }
        ps[((size_t)b * 16 + x) * 64 + t] = s;
        short* dst = &VtB[((size_t)b * ND + t) * NKC + kb];
        *(short8*)&dst[0] = w0;
        *(short8*)&dst[8] = w1;
    }
}

// ---------------------------------------------------------------------------
// attn_new (R8-proven): heavy path reads MFMA-ready bf16 KeB/VtB; broadcast
// reads ps (4 KB). grid (68, 32).
// ---------------------------------------------------------------------------
__global__ __launch_bounds__(256) void attn_new(
    const float* __restrict__ Q,  const short* __restrict__ KeB,
    const short* __restrict__ VtB, const float* __restrict__ ps,
    float* __restrict__ out)
{
    const int x = blockIdx.x, b = blockIdx.y, t = threadIdx.x;

    if (x >= 8) {
        __shared__ float mvs[64];
        if (t < 64) {
            float s = 0.f;
#pragma unroll
            for (int i = 0; i < 16; ++i) s += ps[((size_t)b * 16 + i) * 64 + t];
            mvs[t] = s * (1.f / 256.f);
        }
        __syncthreads();
        const int r0 = 256 + (x - 8) * 64;
#pragma unroll
        for (int i = 0; i < 4; ++i) {
            int idx = i * 256 + t, row = idx >> 4, q = idx & 15;
            *(float4*)&out[((size_t)b * NS + r0 + row) * ND + q * 4] =
                *(const float4*)&mvs[q * 4];
        }
        return;
    }

    const int s0 = x * 32;
    const int wave = t >> 6, lane = t & 63, lm = lane & 15, g = lane >> 4;
    __shared__ short Qs[32 * QSTR];     //  4.6 KB
    __shared__ short PsB[32 * PBSTR];   // 16.9 KB
    __shared__ short VfT[64 * VSTR];    // 33.8 KB
    __shared__ float rsums[32][4];      // [row][wave]

    // stage Q rows -> bf16
    {
        int row = t >> 3, dq = t & 7;
        size_t off = ((size_t)b * NS + s0 + row) * ND + dq * 8;
        float4 q0 = *(const float4*)&Q[off], q1 = *(const float4*)&Q[off + 4];
        short8 w;
        w[0] = f2bf(q0.x); w[1] = f2bf(q0.y); w[2] = f2bf(q0.z); w[3] = f2bf(q0.w);
        w[4] = f2bf(q1.x); w[5] = f2bf(q1.y); w[6] = f2bf(q1.z); w[7] = f2bf(q1.w);
        *(short8*)&Qs[row * QSTR + dq * 8] = w;
    }
    // stage VfT: straight bf16 copy of VtB[b][d][0..255] (32 KB)
    {
        const int d = t >> 2, q4 = t & 3;
        const short* src = &VtB[((size_t)b * ND + d) * NKC + q4 * 64];
#pragma unroll
        for (int i = 0; i < 8; ++i)
            *(short8*)&VfT[d * VSTR + q4 * 64 + i * 8] = *(const short8*)&src[i * 8];
    }
    __syncthreads();

    // phase 1: P = Q*(Ke+Eb)^T/8; B-frag = direct short8 load from KeB
    f32x4 accP[2][4];
#pragma unroll
    for (int rt = 0; rt < 2; ++rt)
#pragma unroll
        for (int kk = 0; kk < 4; ++kk) accP[rt][kk] = (f32x4){0.f, 0.f, 0.f, 0.f};
#pragma unroll
    for (int kk = 0; kk < 4; ++kk) {
        int kt = wave * 4 + kk;
#pragma unroll
        for (int ks2 = 0; ks2 < 2; ++ks2) {
            short8 bf = *(const short8*)&KeB[((size_t)b * NKC + kt * 16 + lm) * ND + ks2 * 32 + g * 8];
#pragma unroll
            for (int rt = 0; rt < 2; ++rt) {
                short8 aq = *(const short8*)&Qs[(rt * 16 + lm) * QSTR + ks2 * 32 + g * 8];
                accP[rt][kk] = __builtin_amdgcn_mfma_f32_16x16x32_bf16(aq, bf, accP[rt][kk], 0, 0, 0);
            }
        }
    }
    // exp (max-free) + per-row partial sums
#pragma unroll
    for (int rt = 0; rt < 2; ++rt)
#pragma unroll
        for (int r = 0; r < 4; ++r) {
            float s = 0.f;
            int rowg = s0 + rt * 16 + g * 4 + r;
#pragma unroll
            for (int kk = 0; kk < 4; ++kk) {
                int col = wave * 64 + kk * 16 + lm;
                float e = (col >= rowg) ? __expf(accP[rt][kk][r] * 0.125f) : 0.f;
                accP[rt][kk][r] = e;
                s += e;
            }
#pragma unroll
            for (int off = 1; off <= 8; off <<= 1) s += __shfl_xor(s, off, 64);
            if (lm == 0) rsums[rt * 16 + g * 4 + r][wave] = s;
        }
    __syncthreads();
    // normalize -> PsB bf16
#pragma unroll
    for (int rt = 0; rt < 2; ++rt)
#pragma unroll
        for (int r = 0; r < 4; ++r) {
            float4 rs = *(const float4*)&rsums[rt * 16 + g * 4 + r][0];
            float inv = 1.f / (rs.x + rs.y + rs.z + rs.w);
#pragma unroll
            for (int kk = 0; kk < 4; ++kk)
                PsB[(rt * 16 + g * 4 + r) * PBSTR + wave * 64 + kk * 16 + lm] =
                    f2bf(accP[rt][kk][r] * inv);
        }
    __syncthreads();

    // phase 2: out = P * VfT; k < 32x provably zero -> start at ks = x
    f32x4 oa[2];
    oa[0] = (f32x4){0.f, 0.f, 0.f, 0.f};
    oa[1] = (f32x4){0.f, 0.f, 0.f, 0.f};
    for (int ks = x; ks < 8; ++ks) {
        short8 bv = *(const short8*)&VfT[(wave * 16 + lm) * VSTR + ks * 32 + g * 8];
#pragma unroll
        for (int rt = 0; rt < 2; ++rt) {
            short8 av = *(const short8*)&PsB[(rt * 16 + lm) * PBSTR + ks * 32 + g * 8];
            oa[rt] = __builtin_amdgcn_mfma_f32_16x16x32_bf16(av, bv, oa[rt], 0, 0, 0);
        }
    }
#pragma unroll
    for (int rt = 0; rt < 2; ++rt)
#pragma unroll
        for (int r = 0; r < 4; ++r)
            out[((size_t)b * NS + s0 + rt * 16 + g * 4 + r) * ND + wave * 16 + lm] = oa[rt][r];
}

// ---------------------------------------------------------------------------
// attn_old (small-ws fallback, R6-proven): folds 2 partials in registers.
// ---------------------------------------------------------------------------
__global__ __launch_bounds__(256) void attn_old(
    const float* __restrict__ Q,  const float* __restrict__ base,
    const float* __restrict__ Eb, const float* __restrict__ Fb,
    float* __restrict__ out)
{
    const int x = blockIdx.x, b = blockIdx.y, t = threadIdx.x;
    const float* KeTa = base;
    const float* Vfa  = base + NKE;
    const float* KeTb = base + 2 * NKE;
    const float* Vfb  = base + 3 * NKE;

    if (x >= 8) {
        __shared__ float pq[16][64];
        __shared__ float mvs[64];
        const int kg = t >> 4, dq = t & 15;
        float4 s4 = (float4){0.f, 0.f, 0.f, 0.f};
        for (int p = 0; p < 16; ++p) {
            int k = p * 16 + kg;
            float4 v = *(const float4*)&Vfa[((size_t)b * NKC + k) * ND + dq * 4];
            float4 u = *(const float4*)&Vfb[((size_t)b * NKC + k) * ND + dq * 4];
            float fb = Fb[k];
            s4.x += (v.x + u.x) + fb; s4.y += (v.y + u.y) + fb;
            s4.z += (v.z + u.z) + fb; s4.w += (v.w + u.w) + fb;
        }
        *(float4*)&pq[kg][dq * 4] = s4;
        __syncthreads();
        if (t < 64) {
            float m = 0.f;
#pragma unroll
            for (int i = 0; i < 16; ++i) m += pq[i][t];
            mvs[t] = m * (1.f / 256.f);
        }
        __syncthreads();
        const int r0 = 256 + (x - 8) * 64;
#pragma unroll
        for (int i = 0; i < 4; ++i) {
            int idx = i * 256 + t, row = idx >> 4, q = idx & 15;
            *(float4*)&out[((size_t)b * NS + r0 + row) * ND + q * 4] =
                *(const float4*)&mvs[q * 4];
        }
        return;
    }

    const int s0 = x * 32;
    const int wave = t >> 6, lane = t & 63, lm = lane & 15, g = lane >> 4;
    __shared__ short Qs[32 * QSTR];
    __shared__ short PsB[32 * PBSTR];
    __shared__ short VfT[64 * VSTR];
    __shared__ float rsums[32][4];

    {
        int row = t >> 3, dq = t & 7;
        size_t off = ((size_t)b * NS + s0 + row) * ND + dq * 8;
        float4 q0 = *(const float4*)&Q[off], q1 = *(const float4*)&Q[off + 4];
        short8 w;
        w[0] = f2bf(q0.x); w[1] = f2bf(q0.y); w[2] = f2bf(q0.z); w[3] = f2bf(q0.w);
        w[4] = f2bf(q1.x); w[5] = f2bf(q1.y); w[6] = f2bf(q1.z); w[7] = f2bf(q1.w);
        *(short8*)&Qs[row * QSTR + dq * 8] = w;
    }
    {
        const int dB = t & 31, sB = t >> 5;
#pragma unroll
        for (int pass = 0; pass < 4; ++pass) {
            int kb = pass * 64 + sB * 8;
            float2 v[8]; float fb[8];
#pragma unroll
            for (int i = 0; i < 8; ++i) {
                float2 a = *(const float2*)&Vfa[((size_t)b * NKC + kb + i) * ND + dB * 2];
                float2 c = *(const float2*)&Vfb[((size_t)b * NKC + kb + i) * ND + dB * 2];
                v[i]  = (float2){a.x + c.x, a.y + c.y};
                fb[i] = Fb[kb + i];
            }
            short8 w0, w1;
#pragma unroll
            for (int i = 0; i < 8; ++i) {
                w0[i] = f2bf(v[i].x + fb[i]);
                w1[i] = f2bf(v[i].y + fb[i]);
            }
            *(short8*)&VfT[(dB * 2 + 0) * VSTR + kb] = w0;
            *(short8*)&VfT[(dB * 2 + 1) * VSTR + kb] = w1;
        }
    }
    __syncthreads();

    f32x4 accP[2][4];
#pragma unroll
    for (int rt = 0; rt < 2; ++rt)
#pragma unroll
        for (int kk = 0; kk < 4; ++kk) accP[rt][kk] = (f32x4){0.f, 0.f, 0.f, 0.f};
#pragma unroll
    for (int kk = 0; kk < 4; ++kk) {
        int kt = wave * 4 + kk;
        float ebv = Eb[kt * 16 + lm];
#pragma unroll
        for (int ks2 = 0; ks2 < 2; ++ks2) {
            const size_t koff = ((size_t)b * NKC + kt * 16 + lm) * ND + ks2 * 32 + g * 8;
            float4 c0 = *(const float4*)&KeTa[koff], c1 = *(const float4*)&KeTa[koff + 4];
            float4 e0 = *(const float4*)&KeTb[koff], e1 = *(const float4*)&KeTb[koff + 4];
            short8 bf;
            bf[0] = f2bf((c0.x + e0.x) + ebv); bf[1] = f2bf((c0.y + e0.y) + ebv);
            bf[2] = f2bf((c0.z + e0.z) + ebv); bf[3] = f2bf((c0.w + e0.w) + ebv);
            bf[4] = f2bf((c1.x + e1.x) + ebv); bf[5] = f2bf((c1.y + e1.y) + ebv);
            bf[6] = f2bf((c1.z + e1.z) + ebv); bf[7] = f2bf((c1.w + e1.w) + ebv);
#pragma unroll
            for (int rt = 0; rt < 2; ++rt) {
                short8 aq = *(const short8*)&Qs[(rt * 16 + lm) * QSTR + ks2 * 32 + g * 8];
                accP[rt][kk] = __builtin_amdgcn_mfma_f32_16x16x32_bf16(aq, bf, accP[rt][kk], 0, 0, 0);
            }
        }
    }
#pragma unroll
    for (int rt = 0; rt < 2; ++rt)
#pragma unroll
        for (int r = 0; r < 4; ++r) {
            float s = 0.f;
            int rowg = s0 + rt * 16 + g * 4 + r;
#pragma unroll
            for (int kk = 0; kk < 4; ++kk) {
                int col = wave * 64 + kk * 16 + lm;
                float e = (col >= rowg) ? __expf(accP[rt][kk][r] * 0.125f) : 0.f;
                accP[rt][kk][r] = e;
                s += e;
            }
#pragma unroll
            for (int off = 1; off <= 8; off <<= 1) s += __shfl_xor(s, off, 64);
            if (lm == 0) rsums[rt * 16 + g * 4 + r][wave] = s;
        }
    __syncthreads();
#pragma unroll
    for (int rt = 0; rt < 2; ++rt)
#pragma unroll
        for (int r = 0; r < 4; ++r) {
            float4 rs = *(const float4*)&rsums[rt * 16 + g * 4 + r][0];
            float inv = 1.f / (rs.x + rs.y + rs.z + rs.w);
#pragma unroll
            for (int kk = 0; kk < 4; ++kk)
                PsB[(rt * 16 + g * 4 + r) * PBSTR + wave * 64 + kk * 16 + lm] =
                    f2bf(accP[rt][kk][r] * inv);
        }
    __syncthreads();

    f32x4 oa[2];
    oa[0] = (f32x4){0.f, 0.f, 0.f, 0.f};
    oa[1] = (f32x4){0.f, 0.f, 0.f, 0.f};
    for (int ks = x; ks < 8; ++ks) {
        short8 bv = *(const short8*)&VfT[(wave * 16 + lm) * VSTR + ks * 32 + g * 8];
#pragma unroll
        for (int rt = 0; rt < 2; ++rt) {
            short8 av = *(const short8*)&PsB[(rt * 16 + lm) * PBSTR + ks * 32 + g * 8];
            oa[rt] = __builtin_amdgcn_mfma_f32_16x16x32_bf16(av, bv, oa[rt], 0, 0, 0);
        }
    }
#pragma unroll
    for (int rt = 0; rt < 2; ++rt)
#pragma unroll
        for (int r = 0; r < 4; ++r)
            out[((size_t)b * NS + s0 + rt * 16 + g * 4 + r) * ND + wave * 16 + lm] = oa[rt][r];
}

extern "C" void kernel_launch(void* const* d_in, const int* in_sizes, int n_in,
                              void* d_out, int out_size, void* d_ws, size_t ws_size,
                              hipStream_t stream) {
    (void)in_sizes; (void)n_in; (void)out_size;
    const float* Q  = (const float*)d_in[0];
    const float* K  = (const float*)d_in[1];
    const float* V  = (const float*)d_in[2];
    const float* Ew = (const float*)d_in[3];
    const float* Eb = (const float*)d_in[4];
    const float* Fw = (const float*)d_in[5];
    const float* Fb = (const float*)d_in[6];
    float* out = (float*)d_out;

    float* base = (float*)d_ws;
    const size_t MB = 1024u * 1024u;

    if (ws_size >= 15 * MB) {
        // partials 8 MB | EwB/FwB 4 MB | KeB 1 MB | VtB 1 MB | ps 128 KB
        short* EwB = (short*)(base + 4 * NKE);          // [ 8,10) MB
        short* FwB = EwB + (size_t)NKC * NS;            // [10,12) MB
        short* KeB = FwB + (size_t)NKC * NS;            // [12,13) MB
        short* VtB = KeB + NKE;                         // [13,14) MB
        float* ps  = (float*)(VtB + NKE);               // [14,14.125) MB
        prep<<<dim3(1024), 256, 0, stream>>>(Ew, Fw, EwB, FwB);
        proj_sk<short><<<dim3(512), 256, 0, stream>>>(EwB, FwB, K, V, base);
        fuse<<<dim3(16, NB), 256, 0, stream>>>(base, Eb, Fb, KeB, VtB, ps);
        attn_new<<<dim3(68, NB), 256, 0, stream>>>(Q, KeB, VtB, ps, out);
    } else {
        proj_sk<float><<<dim3(512), 256, 0, stream>>>(Ew, Fw, K, V, base);
        attn_old<<<dim3(68, NB), 256, 0, stream>>>(Q, base, Eb, Fb, out);
    }
}